// Round 4
// baseline (1012.177 us; speedup 1.0000x reference)
//
#include <hip/hip_runtime.h>

// LSTM (H=32), B=2048, T=1024, prefix-masked + mean pool + sigmoid classifier.
// Kernels: (1) lengths from mask (+ zero work-queue counter), (2) one-block
// counting sort of batch indices by length, (3) main LSTM: persistent waves,
// each concurrently advancing TWO sequences (dual-ILP hides dep-chain latency
// with 1 wave/SIMD); slots refill from a global atomic queue in descending
// length order (dynamic balance, scheduler-independent). Weights are held in
// 128 named VGPRs, pinned with opaque asm so they cannot be rematerialized.

__device__ __forceinline__ float fast_sigmoid(float x) {
    return __builtin_amdgcn_rcpf(1.0f + __expf(-x));
}
__device__ __forceinline__ float fast_tanh(float x) {
    return fmaf(2.0f, fast_sigmoid(2.0f * x), -1.0f);
}
__device__ __forceinline__ float lane_bcast(float v, int srclane) {
    return __int_as_float(__builtin_amdgcn_readlane(__float_as_int(v), srclane));
}

// ---- macro machinery ----
#define R16A(M) M(0) M(1) M(2) M(3) M(4) M(5) M(6) M(7) \
                M(8) M(9) M(10) M(11) M(12) M(13) M(14) M(15)
#define R16B(M) M(16) M(17) M(18) M(19) M(20) M(21) M(22) M(23) \
                M(24) M(25) M(26) M(27) M(28) M(29) M(30) M(31)
#define R32(M) R16A(M) R16B(M)

#define DECLW(i) float wiA_##i, whA_##i, wiB_##i, whB_##i;
#define LOADW(i) wiA_##i = w_ih[rA32 + (i)]; whA_##i = w_hh[rA32 + (i)]; \
                 wiB_##i = w_ih[rB32 + (i)]; whB_##i = w_hh[rB32 + (i)];
#define PINW(i)  asm volatile("" : "+v"(wiA_##i)); asm volatile("" : "+v"(whA_##i)); \
                 asm volatile("" : "+v"(wiB_##i)); asm volatile("" : "+v"(whB_##i));

// fused x+h FMAs; i<16 -> chains 0/1, i>=16 -> chains 2/3 (8 chains/slot-step)
#define FXH0(i) { const float xm = lane_bcast(xcur, i); const float hm = lane_bcast(hcur, i); \
    aA0 = fmaf(xm, wiA_##i, aA0); aA1 = fmaf(hm, whA_##i, aA1); \
    aB0 = fmaf(xm, wiB_##i, aB0); aB1 = fmaf(hm, whB_##i, aB1); }
#define FXH1(i) { const float xm = lane_bcast(xcur, i); const float hm = lane_bcast(hcur, i); \
    aA2 = fmaf(xm, wiA_##i, aA2); aA3 = fmaf(hm, whA_##i, aA3); \
    aB2 = fmaf(xm, wiB_##i, aB2); aB3 = fmaf(hm, whB_##i, aB3); }

// one LSTM step for slot s (lanes 0..31 hold valid h/c; 32..63 bounded garbage)
#define STEP(s) { \
    const float xn_ = xb##s[min(t##s + 2, Tm1) * 32 + lm]; \
    const float hcur = h##s, xcur = xq##s; \
    float aA0 = bA, aA1 = 0.f, aA2 = 0.f, aA3 = 0.f; \
    float aB0 = bB, aB1 = 0.f, aB2 = 0.f, aB3 = 0.f; \
    R16A(FXH0) R16B(FXH1) \
    const float accA  = (aA0 + aA1) + (aA2 + aA3); \
    const float accB  = (aB0 + aB1) + (aB2 + aB3); \
    const float accA2 = __shfl_xor(accA, 32, 64); \
    const float accB2 = __shfl_xor(accB, 32, 64); \
    const float ig = fast_sigmoid(accA); \
    const float fg = fast_sigmoid(accA2); \
    const float gg = fast_tanh(accB); \
    const float og = fast_sigmoid(accB2); \
    c##s = fg * c##s + ig * gg; \
    h##s = og * fast_tanh(c##s); \
    hsum##s += h##s; \
    xq##s = xp##s; xp##s = xn_; \
    ++t##s; \
}

#define FINISH(s) { \
    const float pooled = hsum##s / (float)L##s; \
    if (lane < 32) out[(size_t)b##s * 32 + lane] = pooled; \
    float contrib = (lane < 32) ? pooled * wcls : 0.0f; \
    contrib += __shfl_down(contrib, 32, 64); \
    contrib += __shfl_down(contrib, 16, 64); \
    contrib += __shfl_down(contrib, 8, 64); \
    contrib += __shfl_down(contrib, 4, 64); \
    contrib += __shfl_down(contrib, 2, 64); \
    contrib += __shfl_down(contrib, 1, 64); \
    if (lane == 0) out[(size_t)B * 32 + b##s] = fast_sigmoid(contrib + bcls); \
}

#define PRIME(s) if (b##s >= 0) { \
    L##s = lens[b##s]; t##s = 0; \
    xb##s = x + (size_t)b##s * T * 32; \
    h##s = 0.f; c##s = 0.f; hsum##s = 0.f; \
    xq##s = xb##s[lm]; \
    xp##s = xb##s[min(1, Tm1) * 32 + lm]; \
}

#define POP(s) { \
    int p_ = 0; \
    if (lane == 0) p_ = atomicAdd(counter, 1); \
    p_ = __shfl(p_, 0, 64); \
    b##s = (p_ < B) ? sidx[B - 1 - p_] : -1; \
}

// ---- kernel 1: sequence lengths from prefix mask (+ zero queue counter) ----
__global__ __launch_bounds__(64)
void len_kernel(const float* __restrict__ mask, int* __restrict__ lens,
                int* __restrict__ counter, int B, int T)
{
    const int b = blockIdx.x;
    if (b == 0 && threadIdx.x == 0) *counter = 0;
    if (b >= B) return;
    const int lane = threadIdx.x;
    const float4* m4 = (const float4*)(mask + (size_t)b * T);
    float s = 0.0f;
    for (int i = lane; i < (T >> 2); i += 64) {
        const float4 v = m4[i];
        s += (v.x + v.y) + (v.z + v.w);
    }
#pragma unroll
    for (int off = 32; off > 0; off >>= 1) s += __shfl_down(s, off, 64);
    if (lane == 0) lens[b] = (int)(s + 0.5f);
}

// ---- kernel 2: one-block counting sort (ascending length) ----
__global__ __launch_bounds__(1024)
void sort_kernel(const int* __restrict__ lens, int* __restrict__ sortedIdx, int B, int T)
{
    __shared__ int hist[1024];
    __shared__ int scan[1024];
    __shared__ int cur[1024];
    const int tid = threadIdx.x;
    if (tid < T) hist[tid] = 0;
    __syncthreads();
    for (int b = tid; b < B; b += blockDim.x)
        atomicAdd(&hist[lens[b] - 1], 1);
    __syncthreads();
    if (tid < T) scan[tid] = hist[tid];
    __syncthreads();
    for (int off = 1; off < T; off <<= 1) {
        int v = 0;
        if (tid >= off && tid < T) v = scan[tid - off];
        __syncthreads();
        if (tid < T) scan[tid] += v;
        __syncthreads();
    }
    if (tid < T) cur[tid] = scan[tid] - hist[tid];
    __syncthreads();
    for (int b = tid; b < B; b += blockDim.x) {
        const int pos = atomicAdd(&cur[lens[b] - 1], 1);
        sortedIdx[pos] = b;
    }
}

// ---- kernel 3: persistent dual-sequence waves with work-stealing ----
__global__ __launch_bounds__(64, 1)
void lstm_main(const float* __restrict__ x,        // [B,T,32]
               const int* __restrict__ lens,       // [B]
               const int* __restrict__ sidx,       // [B] ascending by length
               int* __restrict__ counter,          // work queue head
               const float* __restrict__ w_ih,     // [128,32]
               const float* __restrict__ w_hh,     // [128,32]
               const float* __restrict__ b_ih,     // [128]
               const float* __restrict__ b_hh,     // [128]
               const float* __restrict__ w_cls,    // [1,32]
               const float* __restrict__ b_cls,    // [1]
               float* __restrict__ out,            // pooled [B,32] ++ probs [B]
               int B, int T)
{
    const int lane = threadIdx.x;
    const int lm = lane & 31;
    const int rA32 = lane * 32;            // rows 0..63  : i / f
    const int rB32 = (lane + 64) * 32;     // rows 64..127: g / o
    const int Tm1 = T - 1;

    R32(DECLW)
    R32(LOADW)
    R32(PINW)
    const float bA = b_ih[lane] + b_hh[lane];
    const float bB = b_ih[lane + 64] + b_hh[lane + 64];
    const float wcls = w_cls[lm];
    const float bcls = b_cls[0];

    int b0, b1;
    int L0 = 0, t0 = 0, L1 = 0, t1 = 0;
    const float *xb0 = x, *xb1 = x;
    float h0 = 0.f, c0 = 0.f, hsum0 = 0.f, xq0 = 0.f, xp0 = 0.f;
    float h1 = 0.f, c1 = 0.f, hsum1 = 0.f, xq1 = 0.f, xp1 = 0.f;

    POP(0) POP(1)
    PRIME(0) PRIME(1)

    while (b0 >= 0 && b1 >= 0) {
        const int K = min(L0 - t0, L1 - t1);
        for (int k = 0; k < K; ++k) { STEP(0) STEP(1) }
        if (t0 >= L0) { FINISH(0) POP(0) PRIME(0) }
        if (t1 >= L1) { FINISH(1) POP(1) PRIME(1) }
    }
    while (b0 >= 0) {
        const int K = L0 - t0;
        for (int k = 0; k < K; ++k) { STEP(0) }
        FINISH(0) POP(0) PRIME(0)
    }
    while (b1 >= 0) {
        const int K = L1 - t1;
        for (int k = 0; k < K; ++k) { STEP(1) }
        FINISH(1) POP(1) PRIME(1)
    }
}

extern "C" void kernel_launch(void* const* d_in, const int* in_sizes, int n_in,
                              void* d_out, int out_size, void* d_ws, size_t ws_size,
                              hipStream_t stream)
{
    const float* x     = (const float*)d_in[0];
    const float* mask  = (const float*)d_in[1];
    const float* w_ih  = (const float*)d_in[2];
    const float* w_hh  = (const float*)d_in[3];
    const float* b_ih  = (const float*)d_in[4];
    const float* b_hh  = (const float*)d_in[5];
    const float* w_cls = (const float*)d_in[6];
    const float* b_cls = (const float*)d_in[7];
    float* out = (float*)d_out;

    const int B = out_size / 33;        // pooled B*32 + probs B
    const int T = in_sizes[1] / B;      // mask is [B,T]

    int* lens    = (int*)d_ws;
    int* sidx    = lens + B;
    int* counter = sidx + B;

    len_kernel<<<B, 64, 0, stream>>>(mask, lens, counter, B, T);
    sort_kernel<<<1, 1024, 0, stream>>>(lens, sidx, B, T);
    // 2048 waves: fills every SIMD even at 1 wave/SIMD; extras pop an empty
    // queue and exit (work-stealing is scheduler- and occupancy-independent).
    lstm_main<<<2048, 64, 0, stream>>>(x, lens, sidx, counter, w_ih, w_hh,
                                       b_ih, b_hh, w_cls, b_cls, out, B, T);
}

// Round 5
// 974.194 us; speedup vs baseline: 1.0390x; 1.0390x over previous
//
#include <hip/hip_runtime.h>

// LSTM (H=32), B=2048, T=1024, prefix-masked + mean pool + sigmoid classifier.
// Kernels: (1) lengths from mask, (2) one-block counting sort by length,
// (3) main LSTM: 1024 waves (1 per SIMD, enforced by amdgpu_waves_per_eu(1,1)
// so the register allocator has the full 512-VGPR budget and NO occupancy
// incentive to spill). Wave p runs sorted[p] then sorted[B-1-p] sequentially
// => every wave does ~T+1 steps (deterministic balance, scheduler-independent).
// Weights in 128 named VGPRs (pinned); x via per-lane coalesced vector loads
// prefetched 2 pairs (4 steps) ahead; x and h broadcast by v_readlane.

__device__ __forceinline__ float fast_sigmoid(float x) {
    return __builtin_amdgcn_rcpf(1.0f + __expf(-x));
}
__device__ __forceinline__ float fast_tanh(float x) {
    return fmaf(2.0f, fast_sigmoid(2.0f * x), -1.0f);
}
__device__ __forceinline__ float lane_bcast(float v, int srclane) {
    return __int_as_float(__builtin_amdgcn_readlane(__float_as_int(v), srclane));
}

// ---- macro machinery: 128 named weight registers ----
#define R16A(M) M(0) M(1) M(2) M(3) M(4) M(5) M(6) M(7) \
                M(8) M(9) M(10) M(11) M(12) M(13) M(14) M(15)
#define R16B(M) M(16) M(17) M(18) M(19) M(20) M(21) M(22) M(23) \
                M(24) M(25) M(26) M(27) M(28) M(29) M(30) M(31)
#define R32(M) R16A(M) R16B(M)

#define DECLW(i) float wiA_##i, whA_##i, wiB_##i, whB_##i;
#define LOADW(i) wiA_##i = w_ih[rA32 + (i)]; whA_##i = w_hh[rA32 + (i)]; \
                 wiB_##i = w_ih[rB32 + (i)]; whB_##i = w_hh[rB32 + (i)];
#define PINW(i)  asm volatile("" : "+v"(wiA_##i)); asm volatile("" : "+v"(whA_##i)); \
                 asm volatile("" : "+v"(wiB_##i)); asm volatile("" : "+v"(whB_##i));

// fused x+h FMAs; i<16 -> chains 0/1, i>=16 -> chains 2/3 (8 chains total)
#define FXH0(i) { const float xm = lane_bcast(xcur, i); const float hm = lane_bcast(hcur, i); \
    aA0 = fmaf(xm, wiA_##i, aA0); aA1 = fmaf(hm, whA_##i, aA1); \
    aB0 = fmaf(xm, wiB_##i, aB0); aB1 = fmaf(hm, whB_##i, aB1); }
#define FXH1(i) { const float xm = lane_bcast(xcur, i); const float hm = lane_bcast(hcur, i); \
    aA2 = fmaf(xm, wiA_##i, aA2); aA3 = fmaf(hm, whA_##i, aA3); \
    aB2 = fmaf(xm, wiB_##i, aB2); aB3 = fmaf(hm, whB_##i, aB3); }

// ---- kernel 1: sequence lengths from prefix mask ----
__global__ __launch_bounds__(64)
void len_kernel(const float* __restrict__ mask, int* __restrict__ lens, int B, int T)
{
    const int b = blockIdx.x;
    if (b >= B) return;
    const int lane = threadIdx.x;
    const float4* m4 = (const float4*)(mask + (size_t)b * T);
    float s = 0.0f;
    for (int i = lane; i < (T >> 2); i += 64) {
        const float4 v = m4[i];
        s += (v.x + v.y) + (v.z + v.w);
    }
#pragma unroll
    for (int off = 32; off > 0; off >>= 1) s += __shfl_down(s, off, 64);
    if (lane == 0) lens[b] = (int)(s + 0.5f);
}

// ---- kernel 2: one-block counting sort (ascending length) ----
__global__ __launch_bounds__(1024)
void sort_kernel(const int* __restrict__ lens, int* __restrict__ sortedIdx, int B, int T)
{
    __shared__ int hist[1024];
    __shared__ int scan[1024];
    __shared__ int cur[1024];
    const int tid = threadIdx.x;
    if (tid < T) hist[tid] = 0;
    __syncthreads();
    for (int b = tid; b < B; b += blockDim.x)
        atomicAdd(&hist[lens[b] - 1], 1);
    __syncthreads();
    if (tid < T) scan[tid] = hist[tid];
    __syncthreads();
    for (int off = 1; off < T; off <<= 1) {
        int v = 0;
        if (tid >= off && tid < T) v = scan[tid - off];
        __syncthreads();
        if (tid < T) scan[tid] += v;
        __syncthreads();
    }
    if (tid < T) cur[tid] = scan[tid] - hist[tid];
    __syncthreads();
    for (int b = tid; b < B; b += blockDim.x) {
        const int pos = atomicAdd(&cur[lens[b] - 1], 1);
        sortedIdx[pos] = b;
    }
}

// ---- kernel 3: 1024 waves, complement-paired sequences, 1 wave/EU ----
__global__ __launch_bounds__(64)
__attribute__((amdgpu_waves_per_eu(1, 1)))
void lstm_main(const float* __restrict__ x,        // [B,T,32]
               const int* __restrict__ lens,       // [B]
               const int* __restrict__ sidx,       // [B] ascending by length
               const float* __restrict__ w_ih,     // [128,32]
               const float* __restrict__ w_hh,     // [128,32]
               const float* __restrict__ b_ih,     // [128]
               const float* __restrict__ b_hh,     // [128]
               const float* __restrict__ w_cls,    // [1,32]
               const float* __restrict__ b_cls,    // [1]
               float* __restrict__ out,            // pooled [B,32] ++ probs [B]
               int B, int T)
{
    const int p = blockIdx.x;              // 0 .. B/2-1
    const int lane = threadIdx.x;
    const int lm = lane & 31;
    const int rA32 = lane * 32;            // rows 0..63  : i / f
    const int rB32 = (lane + 64) * 32;     // rows 64..127: g / o
    const int Tm1 = T - 1;

    R32(DECLW)
    R32(LOADW)
    R32(PINW)
    const float bA = b_ih[lane] + b_hh[lane];
    const float bB = b_ih[lane + 64] + b_hh[lane + 64];
    const float wcls = w_cls[lm];
    const float bcls = b_cls[0];

    for (int s = 0; s < 2; ++s) {
        const int b = sidx[s == 0 ? p : (B - 1 - p)];
        const int L = lens[b];
        const float* xb = x + (size_t)b * T * 32;

        float h = 0.0f, c = 0.0f, hsum = 0.0f;
        // x pair-register: lane l holds xb[pair*64 + l]; lanes 0..31 = even
        // step features, lanes 32..63 = odd step features.
        float xq = xb[lm];                          // step 0 features (lo half)
        float xo = xb[32 + lm];                     // step 1 features (use lo idx)
        // NOTE: simpler per-step scheme: keep two single-step regs, prefetch +2
        float xp = xb[min(2, Tm1) * 32 + lm];       // step 2
        float xp2 = xb[min(3, Tm1) * 32 + lm];      // step 3

        for (int t = 0; t < L; ++t) {
            const float xn_ = xb[min(t + 4, Tm1) * 32 + lm];   // prefetch t+4
            const float hcur = h, xcur = xq;
            float aA0 = bA, aA1 = 0.f, aA2 = 0.f, aA3 = 0.f;
            float aB0 = bB, aB1 = 0.f, aB2 = 0.f, aB3 = 0.f;
            R16A(FXH0) R16B(FXH1)
            const float accA  = (aA0 + aA1) + (aA2 + aA3);  // i (k<32) / f (k>=32)
            const float accB  = (aB0 + aB1) + (aB2 + aB3);  // g (k<32) / o (k>=32)
            const float accA2 = __shfl_xor(accA, 32, 64);
            const float accB2 = __shfl_xor(accB, 32, 64);
            const float ig = fast_sigmoid(accA);
            const float fg = fast_sigmoid(accA2);
            const float gg = fast_tanh(accB);
            const float og = fast_sigmoid(accB2);
            c = fg * c + ig * gg;          // lanes >=32: bounded garbage, never read
            h = og * fast_tanh(c);
            hsum += h;
            xq = xo; xo = xp; xp = xp2; xp2 = xn_;  // rotate prefetch pipeline
        }

        const float pooled = hsum / (float)L;       // L >= 1 always
        if (lane < 32) out[(size_t)b * 32 + lane] = pooled;

        float contrib = (lane < 32) ? pooled * wcls : 0.0f;
#pragma unroll
        for (int off = 32; off > 0; off >>= 1)
            contrib += __shfl_down(contrib, off, 64);
        if (lane == 0)
            out[(size_t)B * 32 + b] = fast_sigmoid(contrib + bcls);
    }
}

extern "C" void kernel_launch(void* const* d_in, const int* in_sizes, int n_in,
                              void* d_out, int out_size, void* d_ws, size_t ws_size,
                              hipStream_t stream)
{
    const float* x     = (const float*)d_in[0];
    const float* mask  = (const float*)d_in[1];
    const float* w_ih  = (const float*)d_in[2];
    const float* w_hh  = (const float*)d_in[3];
    const float* b_ih  = (const float*)d_in[4];
    const float* b_hh  = (const float*)d_in[5];
    const float* w_cls = (const float*)d_in[6];
    const float* b_cls = (const float*)d_in[7];
    float* out = (float*)d_out;

    const int B = out_size / 33;        // pooled B*32 + probs B
    const int T = in_sizes[1] / B;      // mask is [B,T]

    int* lens = (int*)d_ws;
    int* sidx = lens + B;

    len_kernel<<<B, 64, 0, stream>>>(mask, lens, B, T);
    sort_kernel<<<1, 1024, 0, stream>>>(lens, sidx, B, T);
    lstm_main<<<B / 2, 64, 0, stream>>>(x, lens, sidx, w_ih, w_hh, b_ih, b_hh,
                                        w_cls, b_cls, out, B, T);
}